// Round 4
// baseline (356.803 us; speedup 1.0000x reference)
//
#include <hip/hip_runtime.h>
#include <cstdint>
#include <cstddef>

// ---------- common ----------
typedef __bf16 bf16x8 __attribute__((ext_vector_type(8)));
typedef float  f32x4  __attribute__((ext_vector_type(4)));
typedef unsigned short u16x8 __attribute__((ext_vector_type(8)));

__device__ __forceinline__ uint16_t f2bf(float f) {
  uint32_t u = __float_as_uint(f);
  u += 0x7fffu + ((u >> 16) & 1u);          // round-to-nearest-even
  return (uint16_t)(u >> 16);
}
__device__ __forceinline__ float bf2f(uint16_t u) {
  return __uint_as_float((uint32_t)u << 16);
}

__device__ __forceinline__ f32x4 mfma16(bf16x8 a, bf16x8 b, f32x4 c) {
  return __builtin_amdgcn_mfma_f32_16x16x32_bf16(a, b, c, 0, 0, 0);
}

#define GLD_TO_LDS16(gptr, lptr)                                                   \
  __builtin_amdgcn_global_load_lds(                                                \
      (const __attribute__((address_space(1))) void*)(gptr),                       \
      (__attribute__((address_space(3))) void*)(lptr), 16, 0, 0)

// ---------- fused fp32 -> bf16 cast of all 4 tensors ----------
__global__ void cvt_all(const float* __restrict__ q, const float* __restrict__ k,
                        const float* __restrict__ w, const float* __restrict__ wo,
                        uint16_t* __restrict__ Xq, uint16_t* __restrict__ Xk,
                        uint16_t* __restrict__ Wb, uint16_t* __restrict__ Wob) {
  int i = blockIdx.x * blockDim.x + threadIdx.x;
  const float* src;
  uint16_t* dst;
  int off;
  if (i < 1048576)      { src = q;  dst = Xq;  off = i; }
  else if (i < 2097152) { src = k;  dst = Xk;  off = i - 1048576; }
  else if (i < 2883584) { src = w;  dst = Wb;  off = i - 2097152; }
  else                  { src = wo; dst = Wob; off = i - 2883584; }
  float4 v = ((const float4*)src)[off];
  ushort4 o;
  o.x = f2bf(v.x); o.y = f2bf(v.y); o.z = f2bf(v.z); o.w = f2bf(v.w);
  ((ushort4*)dst)[off] = o;
}

// ---------- fused Q + KV projection, 128x128 tiles, grid 768 (3 blk/CU) ----
__global__ __launch_bounds__(256)
void gemm_qkv(const uint16_t* __restrict__ Xq, const uint16_t* __restrict__ Xk,
              const uint16_t* __restrict__ Wb, const float* __restrict__ ipb,
              uint16_t* __restrict__ Qb, uint16_t* __restrict__ Kb,
              uint16_t* __restrict__ Vt) {
  __shared__ __align__(16) uint16_t As[128 * 32];
  __shared__ __align__(16) uint16_t Bs[128 * 32];
  const int tid  = threadIdx.x;
  const int wave = tid >> 6, lane = tid & 63;
  const int quad = lane >> 4, l16 = lane & 15;

  const int bid = blockIdx.x;
  const uint16_t *A, *B;
  const float* bias;
  int bm, bn, mode;
  if (bid < 256) {
    mode = 0; A = Xq; B = Wb; bias = ipb;
    bm = bid >> 3; bn = bid & 7;
  } else {
    mode = 1; A = Xk; B = Wb + (1 << 20); bias = ipb + 1024;
    int t = bid - 256; bm = t >> 4; bn = t & 15;
  }
  const int wm = (wave >> 1) << 6, wn = (wave & 1) << 6;
  const int K = 1024;

  f32x4 acc[4][4] = {};

  for (int k0 = 0; k0 < K; k0 += 32) {
    __syncthreads();
#pragma unroll
    for (int j = 0; j < 2; j++) {
      int c   = wave * 128 + j * 64 + lane;
      int row = c >> 2, kc = c & 3;
      const uint16_t* ga = A + (size_t)(bm * 128 + row) * K + k0 + kc * 8;
      GLD_TO_LDS16(ga, As + (size_t)(wave * 128 + j * 64) * 8);
      const uint16_t* gb = B + (size_t)(bn * 128 + row) * K + k0 + kc * 8;
      GLD_TO_LDS16(gb, Bs + (size_t)(wave * 128 + j * 64) * 8);
    }
    __syncthreads();

    bf16x8 af[4], bfr[4];
#pragma unroll
    for (int i = 0; i < 4; i++) {
      af[i]  = *(const bf16x8*)(As + (wm + i * 16 + l16) * 32 + quad * 8);
      bfr[i] = *(const bf16x8*)(Bs + (wn + i * 16 + l16) * 32 + quad * 8);
    }
#pragma unroll
    for (int mi = 0; mi < 4; mi++)
#pragma unroll
      for (int ni = 0; ni < 4; ni++)
        acc[mi][ni] = mfma16(af[mi], bfr[ni], acc[mi][ni]);
  }

#pragma unroll
  for (int mi = 0; mi < 4; mi++)
#pragma unroll
    for (int ni = 0; ni < 4; ni++)
#pragma unroll
      for (int r = 0; r < 4; r++) {
        int gi = bm * 128 + wm + mi * 16 + quad * 4 + r;  // row = t*4+b
        int gf = bn * 128 + wn + ni * 16 + l16;
        float c = acc[mi][ni][r] + bias[gf];
        if (mode == 0) {
          c *= 0.125f;  // HD^-0.5
          int t = gi >> 2, b = gi & 3, h = gf >> 6, d = gf & 63;
          Qb[((((size_t)b * 16 + h) * 1024 + t) << 6) + d] = f2bf(c);
        } else {
          int s = gi >> 2, b = gi & 3;
          if (gf < 1024) {
            int h = gf >> 6, d = gf & 63;
            Kb[((((size_t)b * 16 + h) * 1024 + s) << 6) + d] = f2bf(c);
          } else {
            int fv = gf - 1024, h = fv >> 6, d = fv & 63;
            Vt[((((size_t)b * 16 + h) * 64 + d) << 10) + s] = f2bf(c);
          }
        }
      }
}

// ---------- out-projection, 64x128 tiles, grid 512 (2 blk/CU) ----------
__global__ __launch_bounds__(256)
void gemm_out(const uint16_t* __restrict__ A, const uint16_t* __restrict__ B,
              const float* __restrict__ bias, float* __restrict__ o32) {
  __shared__ __align__(16) uint16_t As[64 * 32];
  __shared__ __align__(16) uint16_t Bs[128 * 32];
  const int tid  = threadIdx.x;
  const int wave = tid >> 6, lane = tid & 63;
  const int quad = lane >> 4, l16 = lane & 15;
  const int bm = blockIdx.x >> 3, bn = blockIdx.x & 7;  // 64 x 8 tiles
  const int wm = (wave >> 1) << 5, wn = (wave & 1) << 6;
  const int K = 1024;

  f32x4 acc[2][4] = {};

  for (int k0 = 0; k0 < K; k0 += 32) {
    __syncthreads();
    {
      int c   = wave * 64 + lane;       // A: 256 chunks, 1/thread
      int row = c >> 2, kc = c & 3;
      const uint16_t* ga = A + (size_t)(bm * 64 + row) * K + k0 + kc * 8;
      GLD_TO_LDS16(ga, As + (size_t)(wave * 64) * 8);
    }
#pragma unroll
    for (int j = 0; j < 2; j++) {       // B: 512 chunks, 2/thread
      int c   = wave * 128 + j * 64 + lane;
      int row = c >> 2, kc = c & 3;
      const uint16_t* gb = B + (size_t)(bn * 128 + row) * K + k0 + kc * 8;
      GLD_TO_LDS16(gb, Bs + (size_t)(wave * 128 + j * 64) * 8);
    }
    __syncthreads();

    bf16x8 af[2], bfr[4];
#pragma unroll
    for (int i = 0; i < 2; i++)
      af[i] = *(const bf16x8*)(As + (wm + i * 16 + l16) * 32 + quad * 8);
#pragma unroll
    for (int i = 0; i < 4; i++)
      bfr[i] = *(const bf16x8*)(Bs + (wn + i * 16 + l16) * 32 + quad * 8);
#pragma unroll
    for (int mi = 0; mi < 2; mi++)
#pragma unroll
      for (int ni = 0; ni < 4; ni++)
        acc[mi][ni] = mfma16(af[mi], bfr[ni], acc[mi][ni]);
  }

#pragma unroll
  for (int mi = 0; mi < 2; mi++)
#pragma unroll
    for (int ni = 0; ni < 4; ni++)
#pragma unroll
      for (int r = 0; r < 4; r++) {
        int gi = bm * 64 + wm + mi * 16 + quad * 4 + r;
        int gf = bn * 128 + wn + ni * 16 + l16;
        o32[(size_t)gi * 1024 + gf] = acc[mi][ni][r] + bias[gf];
      }
}

// ---------- attention: block = (b, head-group-of-4, t-tile16) ----------
// grid 1024 = 4b x 4hg x 64tt -> 4 blocks/CU (VGPR~84<=128, LDS 33.3KB*4<=160KB)
// qb (b,h,t,d) pre-scaled; kb (b,h,s,d); vtb (b,h,d,s); hard (b,t,s) fp32
// attn_out (t,b,h*64+d) bf16.
// avg partials: hg0 -> avg0 fp32; hg1/2/3 -> p1/p2/p3 bf16.
__global__ __launch_bounds__(256, 4)
void attn_kernel(const uint16_t* __restrict__ qb, const uint16_t* __restrict__ kb,
                 const uint16_t* __restrict__ vtb, const float* __restrict__ hard,
                 uint16_t* __restrict__ attn_out, float* __restrict__ avg0,
                 uint16_t* __restrict__ p1, uint16_t* __restrict__ p2,
                 uint16_t* __restrict__ p3) {
  __shared__ __align__(16) uint16_t P[16 * 1032];  // masked unnormalized exp
  __shared__ float redS[4][16];

  const int bid = blockIdx.x;
  const int b  = bid >> 8;
  const int hg = (bid >> 6) & 3;
  const int t0 = (bid & 63) << 4;
  const int tid = threadIdx.x, wave = tid >> 6, lane = tid & 63;
  const int quad = lane >> 4, l16 = lane & 15;
  const int tl = quad * 4;              // C-frag rows tl..tl+3
  const int sbase = wave * 256 + l16;   // C-frag s column base
  const int so = (wave * 4 + quad) * 64;  // avg ownership: row l16, s [so,so+64)

  // hard mask -> 64-bit register mask, bit n*4+r <-> (t=t0+tl+r, s=sbase+n*16)
  unsigned long long hbits = 0ull;
#pragma unroll
  for (int n = 0; n < 16; n++)
#pragma unroll
    for (int r = 0; r < 4; r++) {
      float hv = hard[(size_t)(b * 1024 + t0 + tl + r) * 1024 + sbase + n * 16];
      if (hv != 0.0f) hbits |= (1ull << (n * 4 + r));
    }

  float avg[64];
#pragma unroll
  for (int j = 0; j < 64; j++) avg[j] = 0.f;

  for (int hh = 0; hh < 4; hh++) {
    const int h = hg * 4 + hh;
    const size_t bh = (size_t)(b * 16 + h);

    // Q A-frags (m = l16, k = quad*8+j)
    const uint16_t* qrow = qb + ((bh << 10) + t0 + l16) * 64;
    bf16x8 aq0 = *(const bf16x8*)(qrow + quad * 8);
    bf16x8 aq1 = *(const bf16x8*)(qrow + 32 + quad * 8);

    // streaming S = QK^T: per n compute -> exp -> sum -> masked-exp to P.
    float sm[4] = {0.f, 0.f, 0.f, 0.f};
#pragma unroll
    for (int n = 0; n < 16; n++) {
      const uint16_t* krow = kb + ((bh << 10) + wave * 256 + n * 16 + l16) * 64;
      bf16x8 bk0 = *(const bf16x8*)(krow + quad * 8);
      bf16x8 bk1 = *(const bf16x8*)(krow + 32 + quad * 8);
      f32x4 c = {};
      c = mfma16(aq0, bk0, c);
      c = mfma16(aq1, bk1, c);
#pragma unroll
      for (int r = 0; r < 4; r++) {
        float e = __expf(c[r]);
        sm[r] += e;
        float em = ((hbits >> (n * 4 + r)) & 1ull) ? e : 0.f;
        P[(tl + r) * 1032 + sbase + n * 16] = f2bf(em);
      }
    }
#pragma unroll
    for (int r = 0; r < 4; r++) {
      float s = sm[r];
#pragma unroll
      for (int off = 1; off < 16; off <<= 1) s += __shfl_xor(s, off);
      if (l16 == 0) redS[wave][tl + r] = s;
    }
    __syncthreads();

    float rlrow[4];
#pragma unroll
    for (int r = 0; r < 4; r++)
      rlrow[r] = 1.0f / (redS[0][tl + r] + redS[1][tl + r] +
                         redS[2][tl + r] + redS[3][tl + r]);
    float rlavg = 1.0f / (redS[0][l16] + redS[1][l16] +
                          redS[2][l16] + redS[3][l16]);

    // head-average accumulation: re-read masked exp from P, contiguous-s
#pragma unroll
    for (int j = 0; j < 8; j++) {
      u16x8 pv = *(const u16x8*)(P + l16 * 1032 + so + j * 8);
#pragma unroll
      for (int e = 0; e < 8; e++)
        avg[j * 8 + e] += bf2f(pv[e]) * rlavg;
    }

    // O = (P @ V) * rl : wave covers d in [wave*16, wave*16+16)
    f32x4 oa[4] = {};
#pragma unroll
    for (int kc = 0; kc < 32; kc++) {
      bf16x8 ap = *(const bf16x8*)(P + l16 * 1032 + kc * 32 + quad * 8);
      bf16x8 bv = *(const bf16x8*)(vtb + ((bh << 6) + wave * 16 + l16) * 1024 +
                                   kc * 32 + quad * 8);
      oa[kc & 3] = mfma16(ap, bv, oa[kc & 3]);
    }
#pragma unroll
    for (int r = 0; r < 4; r++) {
      float o = (oa[0][r] + oa[1][r] + oa[2][r] + oa[3][r]) * rlrow[r];
      attn_out[((size_t)(t0 + tl + r) * 4 + b) * 1024 + h * 64 + wave * 16 + l16] =
          f2bf(o);
    }
    __syncthreads();  // protect P/redS before next head overwrites
  }

  // write this head-group's partial sum: row (b, t0+l16), cols so..so+63
  const size_t rowoff = (size_t)(b * 1024 + t0 + l16) * 1024 + so;
  if (hg == 0) {
    float* dst = avg0 + rowoff;
#pragma unroll
    for (int j = 0; j < 16; j++) {
      float4 v = {avg[j * 4], avg[j * 4 + 1], avg[j * 4 + 2], avg[j * 4 + 3]};
      *(float4*)(dst + j * 4) = v;
    }
  } else {
    uint16_t* dst = (hg == 1 ? p1 : hg == 2 ? p2 : p3) + rowoff;
#pragma unroll
    for (int j = 0; j < 8; j++) {
      u16x8 v;
#pragma unroll
      for (int e = 0; e < 8; e++) v[e] = f2bf(avg[j * 8 + e]);
      *(u16x8*)(dst + j * 8) = v;
    }
  }
}

// ---------- combine: avg = (avg0 + p1 + p2 + p3) / 16, in place ----------
__global__ void avg_combine(float* __restrict__ avg, const uint16_t* __restrict__ p1,
                            const uint16_t* __restrict__ p2,
                            const uint16_t* __restrict__ p3) {
  int i = blockIdx.x * blockDim.x + threadIdx.x;  // one float4 per thread
  float4 a = ((const float4*)avg)[i];
  ushort4 q1 = ((const ushort4*)p1)[i];
  ushort4 q2 = ((const ushort4*)p2)[i];
  ushort4 q3 = ((const ushort4*)p3)[i];
  a.x = (a.x + bf2f(q1.x) + bf2f(q2.x) + bf2f(q3.x)) * 0.0625f;
  a.y = (a.y + bf2f(q1.y) + bf2f(q2.y) + bf2f(q3.y)) * 0.0625f;
  a.z = (a.z + bf2f(q1.z) + bf2f(q2.z) + bf2f(q3.z)) * 0.0625f;
  a.w = (a.w + bf2f(q1.w) + bf2f(q2.w) + bf2f(q3.w)) * 0.0625f;
  ((float4*)avg)[i] = a;
}

// ---------- launch ----------
extern "C" void kernel_launch(void* const* d_in, const int* in_sizes, int n_in,
                              void* d_out, int out_size, void* d_ws, size_t ws_size,
                              hipStream_t stream) {
  const float* query = (const float*)d_in[0];
  const float* key   = (const float*)d_in[1];
  const float* hard  = (const float*)d_in[2];
  const float* ipw   = (const float*)d_in[3];
  const float* ipb   = (const float*)d_in[4];
  const float* opw   = (const float*)d_in[5];
  const float* opb   = (const float*)d_in[6];

  char* ws = (char*)d_ws;
  const size_t MB = 1ull << 20;
  uint16_t* Xq  = (uint16_t*)(ws + 0);        // 8 MB (reused as attn_out)
  uint16_t* Xk  = (uint16_t*)(ws + 8 * MB);   // 8 MB (reused as p1)
  uint16_t* Wb  = (uint16_t*)(ws + 16 * MB);  // 6 MB
  uint16_t* Wob = (uint16_t*)(ws + 22 * MB);  // 2 MB
  uint16_t* Qb  = (uint16_t*)(ws + 24 * MB);  // 8 MB (b,h,t,d)
  uint16_t* Kb  = (uint16_t*)(ws + 32 * MB);  // 8 MB (b,h,s,d)
  uint16_t* Vt  = (uint16_t*)(ws + 40 * MB);  // 8 MB (b,h,d,s)
  uint16_t* AO  = Xq;                         // alias: Xq dead after gemm_qkv
  uint16_t* P1  = Xk;                         // alias: Xk dead after gemm_qkv

  float* out = (float*)d_out;
  float* avg = out + 4194304;
  // p2/p3: bf16 partials parked in the out region (dead until gemm_out,
  // which runs after avg_combine consumed them)
  uint16_t* P2 = (uint16_t*)out;
  uint16_t* P3 = (uint16_t*)out + 4194304;

  cvt_all<<<12288, 256, 0, stream>>>(query, key, ipw, opw, Xq, Xk, Wb, Wob);

  // fused Q-proj (256 blocks) + KV-proj (512 blocks)
  gemm_qkv<<<768, 256, 0, stream>>>(Xq, Xk, Wb, ipb, Qb, Kb, Vt);

  // attention: 4 head-groups -> 4 partial avg maps
  attn_kernel<<<1024, 256, 0, stream>>>(Qb, Kb, Vt, hard, AO, avg, P1, P2, P3);

  // avg = (avg0 + p1 + p2 + p3) / 16  (must precede gemm_out: reads out region)
  avg_combine<<<4096, 256, 0, stream>>>(avg, P1, P2, P3);

  // out = AO @ Wo^T + bias (fp32 direct to d_out)
  gemm_out<<<512, 256, 0, stream>>>(AO, Wob, opb, out);
}

// Round 5
// 337.295 us; speedup vs baseline: 1.0578x; 1.0578x over previous
//
#include <hip/hip_runtime.h>
#include <cstdint>
#include <cstddef>

// ---------- common ----------
typedef __bf16 bf16x8 __attribute__((ext_vector_type(8)));
typedef float  f32x4  __attribute__((ext_vector_type(4)));
typedef unsigned short u16x8 __attribute__((ext_vector_type(8)));

__device__ __forceinline__ uint16_t f2bf(float f) {
  uint32_t u = __float_as_uint(f);
  u += 0x7fffu + ((u >> 16) & 1u);          // round-to-nearest-even
  return (uint16_t)(u >> 16);
}
__device__ __forceinline__ float bf2f(uint16_t u) {
  return __uint_as_float((uint32_t)u << 16);
}

__device__ __forceinline__ f32x4 mfma16(bf16x8 a, bf16x8 b, f32x4 c) {
  return __builtin_amdgcn_mfma_f32_16x16x32_bf16(a, b, c, 0, 0, 0);
}

#define GLD_TO_LDS16(gptr, lptr)                                                   \
  __builtin_amdgcn_global_load_lds(                                                \
      (const __attribute__((address_space(1))) void*)(gptr),                       \
      (__attribute__((address_space(3))) void*)(lptr), 16, 0, 0)

// ---------- fused fp32 -> bf16 cast of all 4 tensors ----------
__global__ void cvt_all(const float* __restrict__ q, const float* __restrict__ k,
                        const float* __restrict__ w, const float* __restrict__ wo,
                        uint16_t* __restrict__ Xq, uint16_t* __restrict__ Xk,
                        uint16_t* __restrict__ Wb, uint16_t* __restrict__ Wob) {
  int i = blockIdx.x * blockDim.x + threadIdx.x;
  const float* src;
  uint16_t* dst;
  int off;
  if (i < 1048576)      { src = q;  dst = Xq;  off = i; }
  else if (i < 2097152) { src = k;  dst = Xk;  off = i - 1048576; }
  else if (i < 2883584) { src = w;  dst = Wb;  off = i - 2097152; }
  else                  { src = wo; dst = Wob; off = i - 2883584; }
  float4 v = ((const float4*)src)[off];
  ushort4 o;
  o.x = f2bf(v.x); o.y = f2bf(v.y); o.z = f2bf(v.z); o.w = f2bf(v.w);
  ((ushort4*)dst)[off] = o;
}

// ---------- fused Q + KV projection, 128x128 tiles, grid 768 (3 blk/CU) ----
__global__ __launch_bounds__(256)
void gemm_qkv(const uint16_t* __restrict__ Xq, const uint16_t* __restrict__ Xk,
              const uint16_t* __restrict__ Wb, const float* __restrict__ ipb,
              uint16_t* __restrict__ Qb, uint16_t* __restrict__ Kb,
              uint16_t* __restrict__ Vt) {
  __shared__ __align__(16) uint16_t As[128 * 32];
  __shared__ __align__(16) uint16_t Bs[128 * 32];
  const int tid  = threadIdx.x;
  const int wave = tid >> 6, lane = tid & 63;
  const int quad = lane >> 4, l16 = lane & 15;

  const int bid = blockIdx.x;
  const uint16_t *A, *B;
  const float* bias;
  int bm, bn, mode;
  if (bid < 256) {
    mode = 0; A = Xq; B = Wb; bias = ipb;
    bm = bid >> 3; bn = bid & 7;
  } else {
    mode = 1; A = Xk; B = Wb + (1 << 20); bias = ipb + 1024;
    int t = bid - 256; bm = t >> 4; bn = t & 15;
  }
  const int wm = (wave >> 1) << 6, wn = (wave & 1) << 6;
  const int K = 1024;

  f32x4 acc[4][4] = {};

  for (int k0 = 0; k0 < K; k0 += 32) {
    __syncthreads();
#pragma unroll
    for (int j = 0; j < 2; j++) {
      int c   = wave * 128 + j * 64 + lane;
      int row = c >> 2, kc = c & 3;
      const uint16_t* ga = A + (size_t)(bm * 128 + row) * K + k0 + kc * 8;
      GLD_TO_LDS16(ga, As + (size_t)(wave * 128 + j * 64) * 8);
      const uint16_t* gb = B + (size_t)(bn * 128 + row) * K + k0 + kc * 8;
      GLD_TO_LDS16(gb, Bs + (size_t)(wave * 128 + j * 64) * 8);
    }
    __syncthreads();

    bf16x8 af[4], bfr[4];
#pragma unroll
    for (int i = 0; i < 4; i++) {
      af[i]  = *(const bf16x8*)(As + (wm + i * 16 + l16) * 32 + quad * 8);
      bfr[i] = *(const bf16x8*)(Bs + (wn + i * 16 + l16) * 32 + quad * 8);
    }
#pragma unroll
    for (int mi = 0; mi < 4; mi++)
#pragma unroll
      for (int ni = 0; ni < 4; ni++)
        acc[mi][ni] = mfma16(af[mi], bfr[ni], acc[mi][ni]);
  }

#pragma unroll
  for (int mi = 0; mi < 4; mi++)
#pragma unroll
    for (int ni = 0; ni < 4; ni++)
#pragma unroll
      for (int r = 0; r < 4; r++) {
        int gi = bm * 128 + wm + mi * 16 + quad * 4 + r;  // row = t*4+b
        int gf = bn * 128 + wn + ni * 16 + l16;
        float c = acc[mi][ni][r] + bias[gf];
        if (mode == 0) {
          c *= 0.125f;  // HD^-0.5
          int t = gi >> 2, b = gi & 3, h = gf >> 6, d = gf & 63;
          Qb[((((size_t)b * 16 + h) * 1024 + t) << 6) + d] = f2bf(c);
        } else {
          int s = gi >> 2, b = gi & 3;
          if (gf < 1024) {
            int h = gf >> 6, d = gf & 63;
            Kb[((((size_t)b * 16 + h) * 1024 + s) << 6) + d] = f2bf(c);
          } else {
            int fv = gf - 1024, h = fv >> 6, d = fv & 63;
            Vt[((((size_t)b * 16 + h) * 64 + d) << 10) + s] = f2bf(c);
          }
        }
      }
}

// ---------- out-projection, 64x128 tiles, grid 512 (2 blk/CU) ----------
__global__ __launch_bounds__(256)
void gemm_out(const uint16_t* __restrict__ A, const uint16_t* __restrict__ B,
              const float* __restrict__ bias, float* __restrict__ o32) {
  __shared__ __align__(16) uint16_t As[64 * 32];
  __shared__ __align__(16) uint16_t Bs[128 * 32];
  const int tid  = threadIdx.x;
  const int wave = tid >> 6, lane = tid & 63;
  const int quad = lane >> 4, l16 = lane & 15;
  const int bm = blockIdx.x >> 3, bn = blockIdx.x & 7;  // 64 x 8 tiles
  const int wm = (wave >> 1) << 5, wn = (wave & 1) << 6;
  const int K = 1024;

  f32x4 acc[2][4] = {};

  for (int k0 = 0; k0 < K; k0 += 32) {
    __syncthreads();
    {
      int c   = wave * 64 + lane;       // A: 256 chunks, 1/thread
      int row = c >> 2, kc = c & 3;
      const uint16_t* ga = A + (size_t)(bm * 64 + row) * K + k0 + kc * 8;
      GLD_TO_LDS16(ga, As + (size_t)(wave * 64) * 8);
    }
#pragma unroll
    for (int j = 0; j < 2; j++) {       // B: 512 chunks, 2/thread
      int c   = wave * 128 + j * 64 + lane;
      int row = c >> 2, kc = c & 3;
      const uint16_t* gb = B + (size_t)(bn * 128 + row) * K + k0 + kc * 8;
      GLD_TO_LDS16(gb, Bs + (size_t)(wave * 128 + j * 64) * 8);
    }
    __syncthreads();

    bf16x8 af[2], bfr[4];
#pragma unroll
    for (int i = 0; i < 2; i++)
      af[i] = *(const bf16x8*)(As + (wm + i * 16 + l16) * 32 + quad * 8);
#pragma unroll
    for (int i = 0; i < 4; i++)
      bfr[i] = *(const bf16x8*)(Bs + (wn + i * 16 + l16) * 32 + quad * 8);
#pragma unroll
    for (int mi = 0; mi < 2; mi++)
#pragma unroll
      for (int ni = 0; ni < 4; ni++)
        acc[mi][ni] = mfma16(af[mi], bfr[ni], acc[mi][ni]);
  }

#pragma unroll
  for (int mi = 0; mi < 2; mi++)
#pragma unroll
    for (int ni = 0; ni < 4; ni++)
#pragma unroll
      for (int r = 0; r < 4; r++) {
        int gi = bm * 64 + wm + mi * 16 + quad * 4 + r;
        int gf = bn * 128 + wn + ni * 16 + l16;
        o32[(size_t)gi * 1024 + gf] = acc[mi][ni][r] + bias[gf];
      }
}

// ---------- attention: block = (b, head-group-of-4, t-tile16) ----------
// grid 1024 = 4b x 4hg x 64tt. NOTE launch_bounds(256,2) NOT (256,4):
// (256,4) empirically drives the allocator to a 64-VGPR budget and spills
// ~60 MB to scratch (R2, R4). With (256,2) the binary sits at 84 VGPR,
// spill-free, and occupancy is LDS-limited to 4 blocks/CU anyway
// (33.3 KB x 4 <= 160 KB; 84 VGPR <= 128 allows 4 waves/SIMD).
// qb (b,h,t,d) pre-scaled; kb (b,h,s,d); vtb (b,h,d,s); hard (b,t,s) fp32
// attn_out (t,b,h*64+d) bf16.
// avg partials: hg0 -> avg0 fp32; hg1/2/3 -> p1/p2/p3 bf16.
__global__ __launch_bounds__(256, 2)
void attn_kernel(const uint16_t* __restrict__ qb, const uint16_t* __restrict__ kb,
                 const uint16_t* __restrict__ vtb, const float* __restrict__ hard,
                 uint16_t* __restrict__ attn_out, float* __restrict__ avg0,
                 uint16_t* __restrict__ p1, uint16_t* __restrict__ p2,
                 uint16_t* __restrict__ p3) {
  __shared__ __align__(16) uint16_t P[16 * 1032];  // masked unnormalized exp
  __shared__ float redS[4][16];

  const int bid = blockIdx.x;
  const int b  = bid >> 8;
  const int hg = (bid >> 6) & 3;
  const int t0 = (bid & 63) << 4;
  const int tid = threadIdx.x, wave = tid >> 6, lane = tid & 63;
  const int quad = lane >> 4, l16 = lane & 15;
  const int tl = quad * 4;              // C-frag rows tl..tl+3
  const int sbase = wave * 256 + l16;   // C-frag s column base
  const int so = (wave * 4 + quad) * 64;  // avg ownership: row l16, s [so,so+64)

  // hard mask -> 64-bit register mask, bit n*4+r <-> (t=t0+tl+r, s=sbase+n*16)
  unsigned long long hbits = 0ull;
#pragma unroll
  for (int n = 0; n < 16; n++)
#pragma unroll
    for (int r = 0; r < 4; r++) {
      float hv = hard[(size_t)(b * 1024 + t0 + tl + r) * 1024 + sbase + n * 16];
      if (hv != 0.0f) hbits |= (1ull << (n * 4 + r));
    }

  float avg[64];
#pragma unroll
  for (int j = 0; j < 64; j++) avg[j] = 0.f;

  for (int hh = 0; hh < 4; hh++) {
    const int h = hg * 4 + hh;
    const size_t bh = (size_t)(b * 16 + h);

    // Q A-frags (m = l16, k = quad*8+j)
    const uint16_t* qrow = qb + ((bh << 10) + t0 + l16) * 64;
    bf16x8 aq0 = *(const bf16x8*)(qrow + quad * 8);
    bf16x8 aq1 = *(const bf16x8*)(qrow + 32 + quad * 8);

    // streaming S = QK^T: per n compute -> exp -> sum -> masked-exp to P.
    float sm[4] = {0.f, 0.f, 0.f, 0.f};
#pragma unroll
    for (int n = 0; n < 16; n++) {
      const uint16_t* krow = kb + ((bh << 10) + wave * 256 + n * 16 + l16) * 64;
      bf16x8 bk0 = *(const bf16x8*)(krow + quad * 8);
      bf16x8 bk1 = *(const bf16x8*)(krow + 32 + quad * 8);
      f32x4 c = {};
      c = mfma16(aq0, bk0, c);
      c = mfma16(aq1, bk1, c);
#pragma unroll
      for (int r = 0; r < 4; r++) {
        float e = __expf(c[r]);
        sm[r] += e;
        float em = ((hbits >> (n * 4 + r)) & 1ull) ? e : 0.f;
        P[(tl + r) * 1032 + sbase + n * 16] = f2bf(em);
      }
    }
#pragma unroll
    for (int r = 0; r < 4; r++) {
      float s = sm[r];
#pragma unroll
      for (int off = 1; off < 16; off <<= 1) s += __shfl_xor(s, off);
      if (l16 == 0) redS[wave][tl + r] = s;
    }
    __syncthreads();

    float rlrow[4];
#pragma unroll
    for (int r = 0; r < 4; r++)
      rlrow[r] = 1.0f / (redS[0][tl + r] + redS[1][tl + r] +
                         redS[2][tl + r] + redS[3][tl + r]);
    float rlavg = 1.0f / (redS[0][l16] + redS[1][l16] +
                          redS[2][l16] + redS[3][l16]);

    // head-average accumulation: re-read masked exp from P, contiguous-s
#pragma unroll
    for (int j = 0; j < 8; j++) {
      u16x8 pv = *(const u16x8*)(P + l16 * 1032 + so + j * 8);
#pragma unroll
      for (int e = 0; e < 8; e++)
        avg[j * 8 + e] += bf2f(pv[e]) * rlavg;
    }

    // O = (P @ V) * rl : wave covers d in [wave*16, wave*16+16)
    f32x4 oa[4] = {};
#pragma unroll
    for (int kc = 0; kc < 32; kc++) {
      bf16x8 ap = *(const bf16x8*)(P + l16 * 1032 + kc * 32 + quad * 8);
      bf16x8 bv = *(const bf16x8*)(vtb + ((bh << 6) + wave * 16 + l16) * 1024 +
                                   kc * 32 + quad * 8);
      oa[kc & 3] = mfma16(ap, bv, oa[kc & 3]);
    }
#pragma unroll
    for (int r = 0; r < 4; r++) {
      float o = (oa[0][r] + oa[1][r] + oa[2][r] + oa[3][r]) * rlrow[r];
      attn_out[((size_t)(t0 + tl + r) * 4 + b) * 1024 + h * 64 + wave * 16 + l16] =
          f2bf(o);
    }
    __syncthreads();  // protect P/redS before next head overwrites
  }

  // write this head-group's partial sum: row (b, t0+l16), cols so..so+63
  const size_t rowoff = (size_t)(b * 1024 + t0 + l16) * 1024 + so;
  if (hg == 0) {
    float* dst = avg0 + rowoff;
#pragma unroll
    for (int j = 0; j < 16; j++) {
      float4 v = {avg[j * 4], avg[j * 4 + 1], avg[j * 4 + 2], avg[j * 4 + 3]};
      *(float4*)(dst + j * 4) = v;
    }
  } else {
    uint16_t* dst = (hg == 1 ? p1 : hg == 2 ? p2 : p3) + rowoff;
#pragma unroll
    for (int j = 0; j < 8; j++) {
      u16x8 v;
#pragma unroll
      for (int e = 0; e < 8; e++) v[e] = f2bf(avg[j * 8 + e]);
      *(u16x8*)(dst + j * 8) = v;
    }
  }
}

// ---------- combine: avg = (avg0 + p1 + p2 + p3) / 16, in place ----------
__global__ void avg_combine(float* __restrict__ avg, const uint16_t* __restrict__ p1,
                            const uint16_t* __restrict__ p2,
                            const uint16_t* __restrict__ p3) {
  int i = blockIdx.x * blockDim.x + threadIdx.x;  // one float4 per thread
  float4 a = ((const float4*)avg)[i];
  ushort4 q1 = ((const ushort4*)p1)[i];
  ushort4 q2 = ((const ushort4*)p2)[i];
  ushort4 q3 = ((const ushort4*)p3)[i];
  a.x = (a.x + bf2f(q1.x) + bf2f(q2.x) + bf2f(q3.x)) * 0.0625f;
  a.y = (a.y + bf2f(q1.y) + bf2f(q2.y) + bf2f(q3.y)) * 0.0625f;
  a.z = (a.z + bf2f(q1.z) + bf2f(q2.z) + bf2f(q3.z)) * 0.0625f;
  a.w = (a.w + bf2f(q1.w) + bf2f(q2.w) + bf2f(q3.w)) * 0.0625f;
  ((float4*)avg)[i] = a;
}

// ---------- launch ----------
extern "C" void kernel_launch(void* const* d_in, const int* in_sizes, int n_in,
                              void* d_out, int out_size, void* d_ws, size_t ws_size,
                              hipStream_t stream) {
  const float* query = (const float*)d_in[0];
  const float* key   = (const float*)d_in[1];
  const float* hard  = (const float*)d_in[2];
  const float* ipw   = (const float*)d_in[3];
  const float* ipb   = (const float*)d_in[4];
  const float* opw   = (const float*)d_in[5];
  const float* opb   = (const float*)d_in[6];

  char* ws = (char*)d_ws;
  const size_t MB = 1ull << 20;
  uint16_t* Xq  = (uint16_t*)(ws + 0);        // 8 MB (reused as attn_out)
  uint16_t* Xk  = (uint16_t*)(ws + 8 * MB);   // 8 MB (reused as p1)
  uint16_t* Wb  = (uint16_t*)(ws + 16 * MB);  // 6 MB
  uint16_t* Wob = (uint16_t*)(ws + 22 * MB);  // 2 MB
  uint16_t* Qb  = (uint16_t*)(ws + 24 * MB);  // 8 MB (b,h,t,d)
  uint16_t* Kb  = (uint16_t*)(ws + 32 * MB);  // 8 MB (b,h,s,d)
  uint16_t* Vt  = (uint16_t*)(ws + 40 * MB);  // 8 MB (b,h,d,s)
  uint16_t* AO  = Xq;                         // alias: Xq dead after gemm_qkv
  uint16_t* P1  = Xk;                         // alias: Xk dead after gemm_qkv

  float* out = (float*)d_out;
  float* avg = out + 4194304;
  // p2/p3: bf16 partials parked in the out region (dead until gemm_out,
  // which runs after avg_combine consumed them)
  uint16_t* P2 = (uint16_t*)out;
  uint16_t* P3 = (uint16_t*)out + 4194304;

  cvt_all<<<12288, 256, 0, stream>>>(query, key, ipw, opw, Xq, Xk, Wb, Wob);

  // fused Q-proj (256 blocks) + KV-proj (512 blocks)
  gemm_qkv<<<768, 256, 0, stream>>>(Xq, Xk, Wb, ipb, Qb, Kb, Vt);

  // attention: 4 head-groups -> 4 partial avg maps
  attn_kernel<<<1024, 256, 0, stream>>>(Qb, Kb, Vt, hard, AO, avg, P1, P2, P3);

  // avg = (avg0 + p1 + p2 + p3) / 16  (must precede gemm_out: reads out region)
  avg_combine<<<4096, 256, 0, stream>>>(avg, P1, P2, P3);

  // out = AO @ Wo^T + bias (fp32 direct to d_out)
  gemm_out<<<512, 256, 0, stream>>>(AO, Wob, opb, out);
}